// Round 1
// baseline (1187.683 us; speedup 1.0000x reference)
//
#include <hip/hip_runtime.h>
#include <hip/hip_fp16.h>

#define H 1024
#define E 8
#define TT 8192  // tokens = B*S

typedef __attribute__((ext_vector_type(8))) short bf16x8;
typedef __attribute__((ext_vector_type(4))) float f32x4;

__device__ __forceinline__ unsigned short f2bf(float f) {
  unsigned int u = __float_as_uint(f);
  u += 0x7fffu + ((u >> 16) & 1u);
  return (unsigned short)(u >> 16);
}

__global__ __launch_bounds__(64) void k_init(int* cnt, double* psum) {
  int t = threadIdx.x;
  if (t < E) { cnt[t] = 0; psum[t] = 0.0; }
}

// We [E][H][H] f32 -> wet [E][n][k] bf16 (transposed so MFMA B-frag reads are contiguous in k)
__global__ __launch_bounds__(256) void k_cast_we(const float* __restrict__ we, unsigned short* __restrict__ wet) {
  __shared__ unsigned short tile[32][33];
  int e = blockIdx.z;
  int kb = blockIdx.x << 5, nb = blockIdx.y << 5;
  int t = threadIdx.x;
  int c = t & 31, rr = t >> 5;  // c: 0..31, rr: 0..7
  size_t base = (size_t)e * H * H;
#pragma unroll
  for (int r = 0; r < 4; ++r) {
    int k = kb + rr + (r << 3);
    tile[rr + (r << 3)][c] = f2bf(we[base + (size_t)k * H + nb + c]);
  }
  __syncthreads();
#pragma unroll
  for (int r = 0; r < 4; ++r) {
    int n = nb + rr + (r << 3);
    wet[base + (size_t)n * H + kb + c] = tile[c][rr + (r << 3)];
  }
}

// per-token LN stats (mean, rstd) + cast raw x -> bf16 (experts use raw x)
__global__ __launch_bounds__(256) void k_stats(const float* __restrict__ x, float2* __restrict__ stats,
                                               unsigned short* __restrict__ xb) {
  int tok = blockIdx.x, t = threadIdx.x;
  const float4 v = *reinterpret_cast<const float4*>(&x[(size_t)tok * H + (t << 2)]);
  float s = v.x + v.y + v.z + v.w;
  float ss = v.x * v.x + v.y * v.y + v.z * v.z + v.w * v.w;
#pragma unroll
  for (int off = 32; off; off >>= 1) { s += __shfl_down(s, off); ss += __shfl_down(ss, off); }
  __shared__ float red[4][2];
  int lane = t & 63, wv = t >> 6;
  if (lane == 0) { red[wv][0] = s; red[wv][1] = ss; }
  __syncthreads();
  float fs = red[0][0] + red[1][0] + red[2][0] + red[3][0];
  float fss = red[0][1] + red[1][1] + red[2][1] + red[3][1];
  float mean = fs * (1.0f / H);
  float var = fss * (1.0f / H) - mean * mean;
  float rstd = rsqrtf(var + 1e-5f);
  if (t == 0) stats[tok] = make_float2(mean, rstd);
  ushort4 ob;
  ob.x = f2bf(v.x); ob.y = f2bf(v.y); ob.z = f2bf(v.z); ob.w = f2bf(v.w);
  *reinterpret_cast<ushort4*>(&xb[(size_t)tok * H + (t << 2)]) = ob;
}

// hmid = relu(LN(x) @ w1 + b1), fp32 SIMT, LN fused into A-staging.
// BM=64, BN=128, BK=16; 256 threads; 4x8 per-thread microtile.
__global__ __launch_bounds__(256) void k_router_gemm(const float* __restrict__ x, const float2* __restrict__ stats,
                                                     const float* __restrict__ lsc, const float* __restrict__ lbi,
                                                     const float* __restrict__ w1, const float* __restrict__ b1,
                                                     float* __restrict__ hmid) {
  __shared__ float As[16][68];   // [k][m], 68 pad keeps 16B alignment, spreads banks
  __shared__ float Bs[16][136];  // [k][n]
  __shared__ float2 st[64];
  int bm = blockIdx.x << 6, bn = blockIdx.y << 7;
  int t = threadIdx.x;
  if (t < 64) st[t] = stats[bm + t];
  __syncthreads();
  float acc[4][8];
#pragma unroll
  for (int i = 0; i < 4; ++i)
#pragma unroll
    for (int j = 0; j < 8; ++j) acc[i][j] = 0.f;
  int ty = t >> 4, tx = t & 15;
  int arow = t >> 2, akk = (t & 3) << 2;
  int bkb = t >> 4, bn0 = (t & 15) << 3;
  for (int k0 = 0; k0 < H; k0 += 16) {
    float4 v = *reinterpret_cast<const float4*>(&x[(size_t)(bm + arow) * H + k0 + akk]);
    float4 s4 = *reinterpret_cast<const float4*>(&lsc[k0 + akk]);
    float4 b4 = *reinterpret_cast<const float4*>(&lbi[k0 + akk]);
    float2 mr = st[arow];
    float4 w0 = *reinterpret_cast<const float4*>(&w1[(size_t)(k0 + bkb) * H + bn + bn0]);
    float4 w4 = *reinterpret_cast<const float4*>(&w1[(size_t)(k0 + bkb) * H + bn + bn0 + 4]);
    As[akk + 0][arow] = (v.x - mr.x) * mr.y * s4.x + b4.x;
    As[akk + 1][arow] = (v.y - mr.x) * mr.y * s4.y + b4.y;
    As[akk + 2][arow] = (v.z - mr.x) * mr.y * s4.z + b4.z;
    As[akk + 3][arow] = (v.w - mr.x) * mr.y * s4.w + b4.w;
    *reinterpret_cast<float4*>(&Bs[bkb][bn0]) = w0;
    *reinterpret_cast<float4*>(&Bs[bkb][bn0 + 4]) = w4;
    __syncthreads();
#pragma unroll
    for (int kk = 0; kk < 16; ++kk) {
      float a[4], b[8];
      *reinterpret_cast<float4*>(a) = *reinterpret_cast<const float4*>(&As[kk][ty << 2]);
      *reinterpret_cast<float4*>(b) = *reinterpret_cast<const float4*>(&Bs[kk][tx << 3]);
      *reinterpret_cast<float4*>(b + 4) = *reinterpret_cast<const float4*>(&Bs[kk][(tx << 3) + 4]);
#pragma unroll
      for (int i = 0; i < 4; ++i)
#pragma unroll
        for (int j = 0; j < 8; ++j) acc[i][j] = fmaf(a[i], b[j], acc[i][j]);
    }
    __syncthreads();
  }
  float bb[8];
  *reinterpret_cast<float4*>(bb) = *reinterpret_cast<const float4*>(&b1[bn + (tx << 3)]);
  *reinterpret_cast<float4*>(bb + 4) = *reinterpret_cast<const float4*>(&b1[bn + (tx << 3) + 4]);
#pragma unroll
  for (int i = 0; i < 4; ++i) {
    size_t gr = (size_t)(bm + (ty << 2) + i) * H + bn + (tx << 3);
    float4 o0, o1;
    o0.x = fmaxf(acc[i][0] + bb[0], 0.f);
    o0.y = fmaxf(acc[i][1] + bb[1], 0.f);
    o0.z = fmaxf(acc[i][2] + bb[2], 0.f);
    o0.w = fmaxf(acc[i][3] + bb[3], 0.f);
    o1.x = fmaxf(acc[i][4] + bb[4], 0.f);
    o1.y = fmaxf(acc[i][5] + bb[5], 0.f);
    o1.z = fmaxf(acc[i][6] + bb[6], 0.f);
    o1.w = fmaxf(acc[i][7] + bb[7], 0.f);
    *reinterpret_cast<float4*>(&hmid[gr]) = o0;
    *reinterpret_cast<float4*>(&hmid[gr + 4]) = o1;
  }
}

// logits -> softmax -> top2 -> renorm; build per-expert gather lists; accumulate prob sums (f64)
__global__ __launch_bounds__(256) void k_router_top(const float* __restrict__ hmid, const float* __restrict__ w2,
                                                    const float* __restrict__ b2, int* __restrict__ topE,
                                                    float* __restrict__ topW, int* __restrict__ listIdx,
                                                    float* __restrict__ listW, int* __restrict__ listSlot,
                                                    int* __restrict__ cnt, double* __restrict__ psum) {
  int tok = blockIdx.x, t = threadIdx.x;
  float4 hv = *reinterpret_cast<const float4*>(&hmid[(size_t)tok * H + (t << 2)]);
  float acc[E];
#pragma unroll
  for (int e = 0; e < E; ++e) acc[e] = 0.f;
  const float* wp = &w2[(size_t)(t << 2) * E];
  const float hvv[4] = {hv.x, hv.y, hv.z, hv.w};
#pragma unroll
  for (int i = 0; i < 4; ++i) {
    float4 wa = *reinterpret_cast<const float4*>(&wp[i * E]);
    float4 wb = *reinterpret_cast<const float4*>(&wp[i * E + 4]);
    acc[0] += hvv[i] * wa.x; acc[1] += hvv[i] * wa.y; acc[2] += hvv[i] * wa.z; acc[3] += hvv[i] * wa.w;
    acc[4] += hvv[i] * wb.x; acc[5] += hvv[i] * wb.y; acc[6] += hvv[i] * wb.z; acc[7] += hvv[i] * wb.w;
  }
#pragma unroll
  for (int off = 32; off; off >>= 1)
#pragma unroll
    for (int e = 0; e < E; ++e) acc[e] += __shfl_down(acc[e], off);
  __shared__ float red[4][E];
  int lane = t & 63, wv = t >> 6;
  if (lane == 0)
#pragma unroll
    for (int e = 0; e < E; ++e) red[wv][e] = acc[e];
  __syncthreads();
  if (t == 0) {
    float lg[E], p[E];
    float m = -1e30f;
#pragma unroll
    for (int e = 0; e < E; ++e) {
      lg[e] = red[0][e] + red[1][e] + red[2][e] + red[3][e] + b2[e];
      m = fmaxf(m, lg[e]);
    }
    float s = 0.f;
#pragma unroll
    for (int e = 0; e < E; ++e) { p[e] = expf(lg[e] - m); s += p[e]; }
    float inv = 1.f / s;
#pragma unroll
    for (int e = 0; e < E; ++e) { p[e] *= inv; atomicAdd(&psum[e], (double)p[e]); }
    int e0 = 0;
#pragma unroll
    for (int e = 1; e < E; ++e) if (p[e] > p[e0]) e0 = e;  // strict >: first max (jax tie order)
    int e1 = (e0 == 0) ? 1 : 0;
#pragma unroll
    for (int e = 0; e < E; ++e) if (e != e0 && p[e] > p[e1]) e1 = e;
    float rs = 1.f / (p[e0] + p[e1]);
    float w0 = p[e0] * rs, w1v = p[e1] * rs;
    topE[tok << 1] = e0; topE[(tok << 1) + 1] = e1;
    topW[tok << 1] = w0; topW[(tok << 1) + 1] = w1v;
    int p0 = atomicAdd(&cnt[e0], 1);
    listIdx[e0 * TT + p0] = tok; listW[e0 * TT + p0] = w0; listSlot[e0 * TT + p0] = 0;
    int p1 = atomicAdd(&cnt[e1], 1);
    listIdx[e1 * TT + p1] = tok; listW[e1 * TT + p1] = w1v; listSlot[e1 * TT + p1] = 1;
  }
}

// grouped bf16 MFMA GEMM: for each expert, gathered token rows @ We[e]^T-layout; writes weighted fp16 per-slot
// BM=128 (gathered rows), BN=128, BK=32; 4 waves in 2x2; wave tile 64x64 = 4x4 MFMA 16x16x32 frags.
__global__ __launch_bounds__(256) void k_expert_gemm(const unsigned short* __restrict__ xb,
                                                     const unsigned short* __restrict__ wet,
                                                     const int* __restrict__ listIdx, const float* __restrict__ listW,
                                                     const int* __restrict__ listSlot, const int* __restrict__ cnt,
                                                     unsigned short* __restrict__ ys) {
  int e = blockIdx.z;
  int c = cnt[e];
  int r0 = blockIdx.x << 7;
  if (r0 >= c) return;
  int n0 = blockIdx.y << 7;
  __shared__ short A[128][32];
  __shared__ short B[128][32];
  __shared__ int gi[128];
  __shared__ float gw[128];
  __shared__ int gs[128];
  int t = threadIdx.x;
  if (t < 128) {
    int rr = r0 + t;
    if (rr < c) {
      gi[t] = listIdx[e * TT + rr]; gw[t] = listW[e * TT + rr]; gs[t] = listSlot[e * TT + rr];
    } else {
      gi[t] = -1; gw[t] = 0.f; gs[t] = 0;
    }
  }
  __syncthreads();
  int lane = t & 63, wv = t >> 6;
  int wr = (wv >> 1) << 6, wc = (wv & 1) << 6;
  int l15 = lane & 15, lg = lane >> 4;
  f32x4 acc[4][4];
#pragma unroll
  for (int i = 0; i < 4; ++i)
#pragma unroll
    for (int j = 0; j < 4; ++j) acc[i][j] = f32x4{0.f, 0.f, 0.f, 0.f};
  size_t wbase = (size_t)e * H * H;
  int arow1 = t >> 2, akk = (t & 3) << 3;  // 512 16B chunks per operand, 2 per thread
  int arow2 = arow1 + 64;
  for (int k0 = 0; k0 < H; k0 += 32) {
    int tok1 = gi[arow1]; if (tok1 < 0) tok1 = 0;
    int tok2 = gi[arow2]; if (tok2 < 0) tok2 = 0;
    *reinterpret_cast<int4*>(&A[arow1][akk]) = *reinterpret_cast<const int4*>(&xb[(size_t)tok1 * H + k0 + akk]);
    *reinterpret_cast<int4*>(&A[arow2][akk]) = *reinterpret_cast<const int4*>(&xb[(size_t)tok2 * H + k0 + akk]);
    *reinterpret_cast<int4*>(&B[arow1][akk]) =
        *reinterpret_cast<const int4*>(&wet[wbase + (size_t)(n0 + arow1) * H + k0 + akk]);
    *reinterpret_cast<int4*>(&B[arow2][akk]) =
        *reinterpret_cast<const int4*>(&wet[wbase + (size_t)(n0 + arow2) * H + k0 + akk]);
    __syncthreads();
    bf16x8 af[4], bq[4];
#pragma unroll
    for (int f = 0; f < 4; ++f) {
      af[f] = *reinterpret_cast<const bf16x8*>(&A[wr + (f << 4) + l15][lg << 3]);
      bq[f] = *reinterpret_cast<const bf16x8*>(&B[wc + (f << 4) + l15][lg << 3]);
    }
#pragma unroll
    for (int i = 0; i < 4; ++i)
#pragma unroll
      for (int j = 0; j < 4; ++j)
        acc[i][j] = __builtin_amdgcn_mfma_f32_16x16x32_bf16(af[i], bq[j], acc[i][j], 0, 0, 0);
    __syncthreads();
  }
#pragma unroll
  for (int i = 0; i < 4; ++i) {
#pragma unroll
    for (int r = 0; r < 4; ++r) {
      int row = wr + (i << 4) + (lg << 2) + r;  // C/D: col=lane&15, row=(lane>>4)*4+reg
      int tok = gi[row];
      if (tok < 0) continue;
      float w = gw[row];
      size_t ob = ((size_t)gs[row] * TT + tok) * H + n0 + wc + l15;
#pragma unroll
      for (int j = 0; j < 4; ++j) {
        ys[ob + (j << 4)] = __half_as_ushort(__float2half(w * acc[i][j][r]));
      }
    }
  }
}

// out = y_slot0 + y_slot1 + w0*be[e0] + w1*be[e1]
__global__ __launch_bounds__(256) void k_combine(const unsigned short* __restrict__ ys, const int* __restrict__ topE,
                                                 const float* __restrict__ topW, const float* __restrict__ be,
                                                 float* __restrict__ out) {
  int tok = blockIdx.x, t = threadIdx.x;
  int e0 = topE[tok << 1], e1 = topE[(tok << 1) + 1];
  float w0 = topW[tok << 1], w1v = topW[(tok << 1) + 1];
  int h = t << 2;
  size_t base = (size_t)tok * H + h;
  ushort4 a = *reinterpret_cast<const ushort4*>(&ys[base]);
  ushort4 b = *reinterpret_cast<const ushort4*>(&ys[(size_t)TT * H + base]);
  float4 b0 = *reinterpret_cast<const float4*>(&be[e0 * H + h]);
  float4 b1v = *reinterpret_cast<const float4*>(&be[e1 * H + h]);
  float4 o;
  o.x = __half2float(__ushort_as_half(a.x)) + __half2float(__ushort_as_half(b.x)) + w0 * b0.x + w1v * b1v.x;
  o.y = __half2float(__ushort_as_half(a.y)) + __half2float(__ushort_as_half(b.y)) + w0 * b0.y + w1v * b1v.y;
  o.z = __half2float(__ushort_as_half(a.z)) + __half2float(__ushort_as_half(b.z)) + w0 * b0.z + w1v * b1v.z;
  o.w = __half2float(__ushort_as_half(a.w)) + __half2float(__ushort_as_half(b.w)) + w0 * b0.w + w1v * b1v.w;
  *reinterpret_cast<float4*>(&out[base]) = o;
}

__global__ __launch_bounds__(64) void k_aux(const double* __restrict__ psum, float* __restrict__ outAux) {
  if (threadIdx.x == 0) {
    double a = 0.0;
    for (int e = 0; e < E; ++e) {
      double mp = psum[e] / (double)TT;
      a += mp * log(mp * (double)E + 1e-9);
    }
    outAux[0] = (float)a;
  }
}

extern "C" void kernel_launch(void* const* d_in, const int* in_sizes, int n_in, void* d_out, int out_size, void* d_ws,
                              size_t ws_size, hipStream_t stream) {
  const float* x = (const float*)d_in[0];
  const float* lsc = (const float*)d_in[1];
  const float* lbi = (const float*)d_in[2];
  const float* w1 = (const float*)d_in[3];
  const float* b1 = (const float*)d_in[4];
  const float* w2 = (const float*)d_in[5];
  const float* b2 = (const float*)d_in[6];
  const float* we = (const float*)d_in[7];
  const float* be = (const float*)d_in[8];
  float* out = (float*)d_out;
  char* ws = (char*)d_ws;

  // ws layout (peak ~68.1 MB):
  // [0, 32MB):   hmid f32 (dead after k_router_top) -> overlaid by ys fp16 [2][TT][H]
  // [32, 48MB):  xb bf16
  // [48, 64MB):  wet bf16 (transposed [e][n][k])
  // [64MB, ...): stats/topE/topW/lists/cnt/psum
  float* hmid = (float*)ws;
  unsigned short* ys = (unsigned short*)ws;
  unsigned short* xb = (unsigned short*)(ws + 33554432u);
  unsigned short* wet = (unsigned short*)(ws + 33554432u + 16777216u);
  char* p = ws + 33554432u + 16777216u + 16777216u;
  float2* stats = (float2*)p; p += TT * 8;
  int* topE = (int*)p; p += TT * 2 * 4;
  float* topW = (float*)p; p += TT * 2 * 4;
  int* listIdx = (int*)p; p += E * TT * 4;
  float* listW = (float*)p; p += E * TT * 4;
  int* listSlot = (int*)p; p += E * TT * 4;
  int* cnt = (int*)p; p += 256;
  double* psum = (double*)p; p += 256;

  k_init<<<1, 64, 0, stream>>>(cnt, psum);
  k_cast_we<<<dim3(32, 32, E), 256, 0, stream>>>(we, wet);
  k_stats<<<TT, 256, 0, stream>>>(x, stats, xb);
  k_router_gemm<<<dim3(TT / 64, H / 128), 256, 0, stream>>>(x, stats, lsc, lbi, w1, b1, hmid);
  k_router_top<<<TT, 256, 0, stream>>>(hmid, w2, b2, topE, topW, listIdx, listW, listSlot, cnt, psum);
  k_expert_gemm<<<dim3(TT / 128, H / 128, E), 256, 0, stream>>>(xb, wet, listIdx, listW, listSlot, cnt, ys);
  k_combine<<<TT, 256, 0, stream>>>(ys, topE, topW, be, out);
  k_aux<<<1, 64, 0, stream>>>(psum, out + (size_t)TT * H);
}

// Round 2
// 447.202 us; speedup vs baseline: 2.6558x; 2.6558x over previous
//
#include <hip/hip_runtime.h>
#include <hip/hip_fp16.h>

#define H 1024
#define E 8
#define TT 8192  // tokens = B*S

typedef __attribute__((ext_vector_type(8))) short bf16x8;
typedef __attribute__((ext_vector_type(4))) float f32x4;

__device__ __forceinline__ unsigned short f2bf(float f) {
  unsigned int u = __float_as_uint(f);
  u += 0x7fffu + ((u >> 16) & 1u);
  return (unsigned short)(u >> 16);
}

__global__ __launch_bounds__(64) void k_init(int* cnt, double* psum) {
  int t = threadIdx.x;
  if (t < E) { cnt[t] = 0; psum[t] = 0.0; }
}

// We [E][H][H] f32 -> wet [E][n][k] bf16 (transposed so MFMA B-frag reads are contiguous in k)
__global__ __launch_bounds__(256) void k_cast_we(const float* __restrict__ we, unsigned short* __restrict__ wet) {
  __shared__ unsigned short tile[32][33];
  int e = blockIdx.z;
  int kb = blockIdx.x << 5, nb = blockIdx.y << 5;
  int t = threadIdx.x;
  int c = t & 31, rr = t >> 5;  // c: 0..31, rr: 0..7
  size_t base = (size_t)e * H * H;
#pragma unroll
  for (int r = 0; r < 4; ++r) {
    int k = kb + rr + (r << 3);
    tile[rr + (r << 3)][c] = f2bf(we[base + (size_t)k * H + nb + c]);
  }
  __syncthreads();
#pragma unroll
  for (int r = 0; r < 4; ++r) {
    int n = nb + rr + (r << 3);
    wet[base + (size_t)n * H + kb + c] = tile[c][rr + (r << 3)];
  }
}

// per-token LN stats (mean, rstd) + cast raw x -> bf16 (experts use raw x)
__global__ __launch_bounds__(256) void k_stats(const float* __restrict__ x, float2* __restrict__ stats,
                                               unsigned short* __restrict__ xb) {
  int tok = blockIdx.x, t = threadIdx.x;
  const float4 v = *reinterpret_cast<const float4*>(&x[(size_t)tok * H + (t << 2)]);
  float s = v.x + v.y + v.z + v.w;
  float ss = v.x * v.x + v.y * v.y + v.z * v.z + v.w * v.w;
#pragma unroll
  for (int off = 32; off; off >>= 1) { s += __shfl_down(s, off); ss += __shfl_down(ss, off); }
  __shared__ float red[4][2];
  int lane = t & 63, wv = t >> 6;
  if (lane == 0) { red[wv][0] = s; red[wv][1] = ss; }
  __syncthreads();
  float fs = red[0][0] + red[1][0] + red[2][0] + red[3][0];
  float fss = red[0][1] + red[1][1] + red[2][1] + red[3][1];
  float mean = fs * (1.0f / H);
  float var = fss * (1.0f / H) - mean * mean;
  float rstd = rsqrtf(var + 1e-5f);
  if (t == 0) stats[tok] = make_float2(mean, rstd);
  ushort4 ob;
  ob.x = f2bf(v.x); ob.y = f2bf(v.y); ob.z = f2bf(v.z); ob.w = f2bf(v.w);
  *reinterpret_cast<ushort4*>(&xb[(size_t)tok * H + (t << 2)]) = ob;
}

// hmid = relu(LN(x) @ w1 + b1), fp32 SIMT, LN fused into A-staging.
// BM=64, BN=128, BK=16; 256 threads; 4x8 per-thread microtile.
__global__ __launch_bounds__(256) void k_router_gemm(const float* __restrict__ x, const float2* __restrict__ stats,
                                                     const float* __restrict__ lsc, const float* __restrict__ lbi,
                                                     const float* __restrict__ w1, const float* __restrict__ b1,
                                                     float* __restrict__ hmid) {
  __shared__ float As[16][68];   // [k][m]
  __shared__ float Bs[16][136];  // [k][n]
  __shared__ float2 st[64];
  int bm = blockIdx.x << 6, bn = blockIdx.y << 7;
  int t = threadIdx.x;
  if (t < 64) st[t] = stats[bm + t];
  __syncthreads();
  float acc[4][8];
#pragma unroll
  for (int i = 0; i < 4; ++i)
#pragma unroll
    for (int j = 0; j < 8; ++j) acc[i][j] = 0.f;
  int ty = t >> 4, tx = t & 15;
  int arow = t >> 2, akk = (t & 3) << 2;
  int bkb = t >> 4, bn0 = (t & 15) << 3;
  for (int k0 = 0; k0 < H; k0 += 16) {
    float4 v = *reinterpret_cast<const float4*>(&x[(size_t)(bm + arow) * H + k0 + akk]);
    float4 s4 = *reinterpret_cast<const float4*>(&lsc[k0 + akk]);
    float4 b4 = *reinterpret_cast<const float4*>(&lbi[k0 + akk]);
    float2 mr = st[arow];
    float4 w0 = *reinterpret_cast<const float4*>(&w1[(size_t)(k0 + bkb) * H + bn + bn0]);
    float4 w4 = *reinterpret_cast<const float4*>(&w1[(size_t)(k0 + bkb) * H + bn + bn0 + 4]);
    As[akk + 0][arow] = (v.x - mr.x) * mr.y * s4.x + b4.x;
    As[akk + 1][arow] = (v.y - mr.x) * mr.y * s4.y + b4.y;
    As[akk + 2][arow] = (v.z - mr.x) * mr.y * s4.z + b4.z;
    As[akk + 3][arow] = (v.w - mr.x) * mr.y * s4.w + b4.w;
    *reinterpret_cast<float4*>(&Bs[bkb][bn0]) = w0;
    *reinterpret_cast<float4*>(&Bs[bkb][bn0 + 4]) = w4;
    __syncthreads();
#pragma unroll
    for (int kk = 0; kk < 16; ++kk) {
      float a[4], b[8];
      *reinterpret_cast<float4*>(a) = *reinterpret_cast<const float4*>(&As[kk][ty << 2]);
      *reinterpret_cast<float4*>(b) = *reinterpret_cast<const float4*>(&Bs[kk][tx << 3]);
      *reinterpret_cast<float4*>(b + 4) = *reinterpret_cast<const float4*>(&Bs[kk][(tx << 3) + 4]);
#pragma unroll
      for (int i = 0; i < 4; ++i)
#pragma unroll
        for (int j = 0; j < 8; ++j) acc[i][j] = fmaf(a[i], b[j], acc[i][j]);
    }
    __syncthreads();
  }
  float bb[8];
  *reinterpret_cast<float4*>(bb) = *reinterpret_cast<const float4*>(&b1[bn + (tx << 3)]);
  *reinterpret_cast<float4*>(bb + 4) = *reinterpret_cast<const float4*>(&b1[bn + (tx << 3) + 4]);
#pragma unroll
  for (int i = 0; i < 4; ++i) {
    size_t gr = (size_t)(bm + (ty << 2) + i) * H + bn + (tx << 3);
    float4 o0, o1;
    o0.x = fmaxf(acc[i][0] + bb[0], 0.f);
    o0.y = fmaxf(acc[i][1] + bb[1], 0.f);
    o0.z = fmaxf(acc[i][2] + bb[2], 0.f);
    o0.w = fmaxf(acc[i][3] + bb[3], 0.f);
    o1.x = fmaxf(acc[i][4] + bb[4], 0.f);
    o1.y = fmaxf(acc[i][5] + bb[5], 0.f);
    o1.z = fmaxf(acc[i][6] + bb[6], 0.f);
    o1.w = fmaxf(acc[i][7] + bb[7], 0.f);
    *reinterpret_cast<float4*>(&hmid[gr]) = o0;
    *reinterpret_cast<float4*>(&hmid[gr + 4]) = o1;
  }
}

// logits[tok][e] = hmid[tok,:] @ w2  (wave per token, no atomics)
__global__ __launch_bounds__(256) void k_logits(const float* __restrict__ hmid, const float* __restrict__ w2,
                                                float* __restrict__ logits) {
  int t = threadIdx.x;
  int wv = t >> 6, lane = t & 63;
  int tok = (blockIdx.x << 2) + wv;
  const float* hp = &hmid[(size_t)tok * H + (lane << 4)];
  float h[16];
  *reinterpret_cast<float4*>(h + 0) = *reinterpret_cast<const float4*>(hp + 0);
  *reinterpret_cast<float4*>(h + 4) = *reinterpret_cast<const float4*>(hp + 4);
  *reinterpret_cast<float4*>(h + 8) = *reinterpret_cast<const float4*>(hp + 8);
  *reinterpret_cast<float4*>(h + 12) = *reinterpret_cast<const float4*>(hp + 12);
  float acc[E];
#pragma unroll
  for (int e = 0; e < E; ++e) acc[e] = 0.f;
  const float* wp = &w2[(size_t)(lane << 4) * E];
#pragma unroll
  for (int i = 0; i < 16; ++i) {
    float4 wa = *reinterpret_cast<const float4*>(&wp[i * E]);
    float4 wb = *reinterpret_cast<const float4*>(&wp[i * E + 4]);
    acc[0] = fmaf(h[i], wa.x, acc[0]); acc[1] = fmaf(h[i], wa.y, acc[1]);
    acc[2] = fmaf(h[i], wa.z, acc[2]); acc[3] = fmaf(h[i], wa.w, acc[3]);
    acc[4] = fmaf(h[i], wb.x, acc[4]); acc[5] = fmaf(h[i], wb.y, acc[5]);
    acc[6] = fmaf(h[i], wb.z, acc[6]); acc[7] = fmaf(h[i], wb.w, acc[7]);
  }
#pragma unroll
  for (int off = 1; off < 64; off <<= 1)
#pragma unroll
    for (int e = 0; e < E; ++e) acc[e] += __shfl_xor(acc[e], off);
  if (lane == 0) {
    float4 o0, o1;
    o0.x = acc[0]; o0.y = acc[1]; o0.z = acc[2]; o0.w = acc[3];
    o1.x = acc[4]; o1.y = acc[5]; o1.z = acc[6]; o1.w = acc[7];
    *reinterpret_cast<float4*>(&logits[(size_t)tok * E]) = o0;
    *reinterpret_cast<float4*>(&logits[(size_t)tok * E + 4]) = o1;
  }
}

// thread-per-token: softmax -> top2 -> renorm; wave-aggregated list build + psum
__global__ __launch_bounds__(256) void k_top(const float* __restrict__ logits, const float* __restrict__ b2,
                                             int* __restrict__ topE, float* __restrict__ topW,
                                             int* __restrict__ listIdx, float* __restrict__ listW,
                                             int* __restrict__ listSlot, int* __restrict__ cnt,
                                             double* __restrict__ psum) {
  int t = threadIdx.x, lane = t & 63;
  int tok = (blockIdx.x << 8) + t;
  float lg[E], p[E];
  *reinterpret_cast<float4*>(lg + 0) = *reinterpret_cast<const float4*>(&logits[(size_t)tok * E]);
  *reinterpret_cast<float4*>(lg + 4) = *reinterpret_cast<const float4*>(&logits[(size_t)tok * E + 4]);
  float4 ba = *reinterpret_cast<const float4*>(b2);
  float4 bb = *reinterpret_cast<const float4*>(b2 + 4);
  lg[0] += ba.x; lg[1] += ba.y; lg[2] += ba.z; lg[3] += ba.w;
  lg[4] += bb.x; lg[5] += bb.y; lg[6] += bb.z; lg[7] += bb.w;
  float m = lg[0];
#pragma unroll
  for (int e = 1; e < E; ++e) m = fmaxf(m, lg[e]);
  float s = 0.f;
#pragma unroll
  for (int e = 0; e < E; ++e) { p[e] = __expf(lg[e] - m); s += p[e]; }
  float inv = 1.f / s;
#pragma unroll
  for (int e = 0; e < E; ++e) p[e] *= inv;
  // psum: reduce across the wave, 8 f64 atomics per wave
  {
    float ps[E];
#pragma unroll
    for (int e = 0; e < E; ++e) ps[e] = p[e];
#pragma unroll
    for (int off = 1; off < 64; off <<= 1)
#pragma unroll
      for (int e = 0; e < E; ++e) ps[e] += __shfl_xor(ps[e], off);
    if (lane == 0)
#pragma unroll
      for (int e = 0; e < E; ++e) atomicAdd(&psum[e], (double)ps[e]);
  }
  // top-2 (strict >, first-index-wins = jax tie order)
  int e0 = 0;
#pragma unroll
  for (int e = 1; e < E; ++e) if (p[e] > p[e0]) e0 = e;
  int e1 = (e0 == 0) ? 1 : 0;
#pragma unroll
  for (int e = 0; e < E; ++e) if (e != e0 && p[e] > p[e1]) e1 = e;
  float rs = 1.f / (p[e0] + p[e1]);
  float w0 = p[e0] * rs, w1v = p[e1] * rs;
  topE[tok << 1] = e0; topE[(tok << 1) + 1] = e1;
  topW[tok << 1] = w0; topW[(tok << 1) + 1] = w1v;
  // wave-aggregated list build: 1 atomic per (expert,wave)
  unsigned long long lt = (1ull << lane) - 1ull;
#pragma unroll
  for (int e = 0; e < E; ++e) {
    unsigned long long m0 = __ballot(e0 == e);
    unsigned long long m1 = __ballot(e1 == e);
    int n0 = __popcll(m0), total = n0 + __popcll(m1);
    if (total == 0) continue;  // wave-uniform
    int leader = __ffsll(m0 | m1) - 1;
    int base = 0;
    if (lane == leader) base = atomicAdd(&cnt[e], total);
    base = __shfl(base, leader);
    if (e0 == e) {
      int pos = e * TT + base + __popcll(m0 & lt);
      listIdx[pos] = tok; listW[pos] = w0; listSlot[pos] = 0;
    }
    if (e1 == e) {
      int pos = e * TT + base + n0 + __popcll(m1 & lt);
      listIdx[pos] = tok; listW[pos] = w1v; listSlot[pos] = 1;
    }
  }
}

// grouped bf16 MFMA GEMM: for each expert, gathered token rows @ We[e]^T-layout; writes weighted fp16 per-slot
__global__ __launch_bounds__(256) void k_expert_gemm(const unsigned short* __restrict__ xb,
                                                     const unsigned short* __restrict__ wet,
                                                     const int* __restrict__ listIdx, const float* __restrict__ listW,
                                                     const int* __restrict__ listSlot, const int* __restrict__ cnt,
                                                     unsigned short* __restrict__ ys) {
  int e = blockIdx.z;
  int c = cnt[e];
  int r0 = blockIdx.x << 7;
  if (r0 >= c) return;
  int n0 = blockIdx.y << 7;
  __shared__ short A[128][32];
  __shared__ short B[128][32];
  __shared__ int gi[128];
  __shared__ float gw[128];
  __shared__ int gs[128];
  int t = threadIdx.x;
  if (t < 128) {
    int rr = r0 + t;
    if (rr < c) {
      gi[t] = listIdx[e * TT + rr]; gw[t] = listW[e * TT + rr]; gs[t] = listSlot[e * TT + rr];
    } else {
      gi[t] = -1; gw[t] = 0.f; gs[t] = 0;
    }
  }
  __syncthreads();
  int lane = t & 63, wv = t >> 6;
  int wr = (wv >> 1) << 6, wc = (wv & 1) << 6;
  int l15 = lane & 15, lg = lane >> 4;
  f32x4 acc[4][4];
#pragma unroll
  for (int i = 0; i < 4; ++i)
#pragma unroll
    for (int j = 0; j < 4; ++j) acc[i][j] = f32x4{0.f, 0.f, 0.f, 0.f};
  size_t wbase = (size_t)e * H * H;
  int arow1 = t >> 2, akk = (t & 3) << 3;
  int arow2 = arow1 + 64;
  for (int k0 = 0; k0 < H; k0 += 32) {
    int tok1 = gi[arow1]; if (tok1 < 0) tok1 = 0;
    int tok2 = gi[arow2]; if (tok2 < 0) tok2 = 0;
    *reinterpret_cast<int4*>(&A[arow1][akk]) = *reinterpret_cast<const int4*>(&xb[(size_t)tok1 * H + k0 + akk]);
    *reinterpret_cast<int4*>(&A[arow2][akk]) = *reinterpret_cast<const int4*>(&xb[(size_t)tok2 * H + k0 + akk]);
    *reinterpret_cast<int4*>(&B[arow1][akk]) =
        *reinterpret_cast<const int4*>(&wet[wbase + (size_t)(n0 + arow1) * H + k0 + akk]);
    *reinterpret_cast<int4*>(&B[arow2][akk]) =
        *reinterpret_cast<const int4*>(&wet[wbase + (size_t)(n0 + arow2) * H + k0 + akk]);
    __syncthreads();
    bf16x8 af[4], bq[4];
#pragma unroll
    for (int f = 0; f < 4; ++f) {
      af[f] = *reinterpret_cast<const bf16x8*>(&A[wr + (f << 4) + l15][lg << 3]);
      bq[f] = *reinterpret_cast<const bf16x8*>(&B[wc + (f << 4) + l15][lg << 3]);
    }
#pragma unroll
    for (int i = 0; i < 4; ++i)
#pragma unroll
      for (int j = 0; j < 4; ++j)
        acc[i][j] = __builtin_amdgcn_mfma_f32_16x16x32_bf16(af[i], bq[j], acc[i][j], 0, 0, 0);
    __syncthreads();
  }
#pragma unroll
  for (int i = 0; i < 4; ++i) {
#pragma unroll
    for (int r = 0; r < 4; ++r) {
      int row = wr + (i << 4) + (lg << 2) + r;  // C/D: col=lane&15, row=(lane>>4)*4+reg
      int tok = gi[row];
      if (tok < 0) continue;
      float w = gw[row];
      size_t ob = ((size_t)gs[row] * TT + tok) * H + n0 + wc + l15;
#pragma unroll
      for (int j = 0; j < 4; ++j) {
        ys[ob + (j << 4)] = __half_as_ushort(__float2half(w * acc[i][j][r]));
      }
    }
  }
}

// out = y_slot0 + y_slot1 + w0*be[e0] + w1*be[e1]
__global__ __launch_bounds__(256) void k_combine(const unsigned short* __restrict__ ys, const int* __restrict__ topE,
                                                 const float* __restrict__ topW, const float* __restrict__ be,
                                                 float* __restrict__ out) {
  int tok = blockIdx.x, t = threadIdx.x;
  int e0 = topE[tok << 1], e1 = topE[(tok << 1) + 1];
  float w0 = topW[tok << 1], w1v = topW[(tok << 1) + 1];
  int h = t << 2;
  size_t base = (size_t)tok * H + h;
  ushort4 a = *reinterpret_cast<const ushort4*>(&ys[base]);
  ushort4 b = *reinterpret_cast<const ushort4*>(&ys[(size_t)TT * H + base]);
  float4 b0 = *reinterpret_cast<const float4*>(&be[e0 * H + h]);
  float4 b1v = *reinterpret_cast<const float4*>(&be[e1 * H + h]);
  float4 o;
  o.x = __half2float(__ushort_as_half(a.x)) + __half2float(__ushort_as_half(b.x)) + w0 * b0.x + w1v * b1v.x;
  o.y = __half2float(__ushort_as_half(a.y)) + __half2float(__ushort_as_half(b.y)) + w0 * b0.y + w1v * b1v.y;
  o.z = __half2float(__ushort_as_half(a.z)) + __half2float(__ushort_as_half(b.z)) + w0 * b0.z + w1v * b1v.z;
  o.w = __half2float(__ushort_as_half(a.w)) + __half2float(__ushort_as_half(b.w)) + w0 * b0.w + w1v * b1v.w;
  *reinterpret_cast<float4*>(&out[base]) = o;
}

__global__ __launch_bounds__(64) void k_aux(const double* __restrict__ psum, float* __restrict__ outAux) {
  if (threadIdx.x == 0) {
    double a = 0.0;
    for (int e = 0; e < E; ++e) {
      double mp = psum[e] / (double)TT;
      a += mp * log(mp * (double)E + 1e-9);
    }
    outAux[0] = (float)a;
  }
}

extern "C" void kernel_launch(void* const* d_in, const int* in_sizes, int n_in, void* d_out, int out_size, void* d_ws,
                              size_t ws_size, hipStream_t stream) {
  const float* x = (const float*)d_in[0];
  const float* lsc = (const float*)d_in[1];
  const float* lbi = (const float*)d_in[2];
  const float* w1 = (const float*)d_in[3];
  const float* b1 = (const float*)d_in[4];
  const float* w2 = (const float*)d_in[5];
  const float* b2 = (const float*)d_in[6];
  const float* we = (const float*)d_in[7];
  const float* be = (const float*)d_in[8];
  float* out = (float*)d_out;
  char* ws = (char*)d_ws;

  // ws layout:
  // [0, 32MB):   hmid f32 (dead after k_logits) -> overlaid by ys fp16 [2][TT][H]
  // [32, 48MB):  xb bf16
  // [48, 64MB):  wet bf16 (transposed [e][n][k])
  // [64MB, ...): stats/topE/topW/lists/cnt/psum/logits
  float* hmid = (float*)ws;
  unsigned short* ys = (unsigned short*)ws;
  unsigned short* xb = (unsigned short*)(ws + 33554432u);
  unsigned short* wet = (unsigned short*)(ws + 33554432u + 16777216u);
  char* p = ws + 33554432u + 16777216u + 16777216u;
  float2* stats = (float2*)p; p += TT * 8;
  int* topE = (int*)p; p += TT * 2 * 4;
  float* topW = (float*)p; p += TT * 2 * 4;
  int* listIdx = (int*)p; p += E * TT * 4;
  float* listW = (float*)p; p += E * TT * 4;
  int* listSlot = (int*)p; p += E * TT * 4;
  int* cnt = (int*)p; p += 256;
  double* psum = (double*)p; p += 256;
  float* logits = (float*)p; p += TT * E * 4;

  k_init<<<1, 64, 0, stream>>>(cnt, psum);
  k_cast_we<<<dim3(32, 32, E), 256, 0, stream>>>(we, wet);
  k_stats<<<TT, 256, 0, stream>>>(x, stats, xb);
  k_router_gemm<<<dim3(TT / 64, H / 128), 256, 0, stream>>>(x, stats, lsc, lbi, w1, b1, hmid);
  k_logits<<<TT / 4, 256, 0, stream>>>(hmid, w2, logits);
  k_top<<<TT / 256, 256, 0, stream>>>(logits, b2, topE, topW, listIdx, listW, listSlot, cnt, psum);
  k_expert_gemm<<<dim3(TT / 128, H / 128, E), 256, 0, stream>>>(xb, wet, listIdx, listW, listSlot, cnt, ys);
  k_combine<<<TT, 256, 0, stream>>>(ys, topE, topW, be, out);
  k_aux<<<1, 64, 0, stream>>>(psum, out + (size_t)TT * H);
}

// Round 3
// 227.493 us; speedup vs baseline: 5.2207x; 1.9658x over previous
//
#include <hip/hip_runtime.h>
#include <hip/hip_fp16.h>

#define H 1024
#define E 8
#define TT 8192  // tokens = B*S

typedef __attribute__((ext_vector_type(8))) short bf16x8;
typedef __attribute__((ext_vector_type(4))) float f32x4;

__device__ __forceinline__ unsigned short f2bf(float f) {
  unsigned int u = __float_as_uint(f);
  u += 0x7fffu + ((u >> 16) & 1u);
  return (unsigned short)(u >> 16);
}

// LDS tile addressing: [128 rows][32 bf16] = row stride 64B, 4 chunks of 16B.
// XOR swizzle chunk' = c ^ ((row>>1)&3): conflict-free staged writes AND mfma b128 reads.
__device__ __forceinline__ int swz(int row, int c) {
  return (row << 5) | (((c ^ (row >> 1)) & 3) << 3);
}

__global__ __launch_bounds__(64) void k_init(int* cnt, double* psum) {
  int t = threadIdx.x;
  if (t < E) { cnt[t] = 0; psum[t] = 0.0; }
}

// We [E][H][H] f32 -> wet [E][n][k] bf16
__global__ __launch_bounds__(256) void k_cast_we(const float* __restrict__ we, unsigned short* __restrict__ wet) {
  __shared__ unsigned short tile[32][33];
  int e = blockIdx.z;
  int kb = blockIdx.x << 5, nb = blockIdx.y << 5;
  int t = threadIdx.x;
  int cc = t & 31, rr = t >> 5;
  size_t base = (size_t)e * H * H;
#pragma unroll
  for (int r = 0; r < 4; ++r) {
    int k = kb + rr + (r << 3);
    tile[rr + (r << 3)][cc] = f2bf(we[base + (size_t)k * H + nb + cc]);
  }
  __syncthreads();
#pragma unroll
  for (int r = 0; r < 4; ++r) {
    int n = nb + rr + (r << 3);
    wet[base + (size_t)n * H + kb + cc] = tile[cc][rr + (r << 3)];
  }
}

// w1 [k][n] f32 (scaled by lsc[k]) -> w1h/w1l [n][k] bf16 hi/lo split
__global__ __launch_bounds__(256) void k_cast_w1(const float* __restrict__ w1, const float* __restrict__ lsc,
                                                 unsigned short* __restrict__ w1h, unsigned short* __restrict__ w1l) {
  __shared__ float tile[32][33];
  int kb = blockIdx.x << 5, nb = blockIdx.y << 5;
  int t = threadIdx.x;
  int cc = t & 31, rr = t >> 5;
#pragma unroll
  for (int r = 0; r < 4; ++r) {
    int k = kb + rr + (r << 3);
    tile[rr + (r << 3)][cc] = w1[(size_t)k * H + nb + cc] * lsc[k];
  }
  __syncthreads();
#pragma unroll
  for (int r = 0; r < 4; ++r) {
    int n = nb + rr + (r << 3);
    float v = tile[cc][rr + (r << 3)];
    unsigned short h = f2bf(v);
    float hv = __uint_as_float((unsigned)h << 16);
    unsigned short l = f2bf(v - hv);
    w1h[(size_t)n * H + kb + cc] = h;
    w1l[(size_t)n * H + kb + cc] = l;
  }
}

// part[64][H]: block bk sums lbi[k]*w1[k][n] over its 16 k's (deterministic)
__global__ __launch_bounds__(256) void k_b1a(const float* __restrict__ w1, const float* __restrict__ lbi,
                                             float* __restrict__ part) {
  int bk = blockIdx.x, t = threadIdx.x;
  float a0 = 0, a1 = 0, a2 = 0, a3 = 0;
  for (int kk = 0; kk < 16; ++kk) {
    int k = (bk << 4) + kk;
    float lb = lbi[k];
    const float* row = &w1[(size_t)k * H];
    a0 = fmaf(lb, row[t], a0);
    a1 = fmaf(lb, row[t + 256], a1);
    a2 = fmaf(lb, row[t + 512], a2);
    a3 = fmaf(lb, row[t + 768], a3);
  }
  part[bk * H + t] = a0;
  part[bk * H + t + 256] = a1;
  part[bk * H + t + 512] = a2;
  part[bk * H + t + 768] = a3;
}

__global__ __launch_bounds__(256) void k_b1b(const float* __restrict__ part, const float* __restrict__ b1,
                                             float* __restrict__ b1eff) {
  int n = (blockIdx.x << 8) + threadIdx.x;
  float s = b1[n];
  for (int j = 0; j < 64; ++j) s += part[j * H + n];
  b1eff[n] = s;
}

// per-token LN stats (mean, rstd) + cast raw x -> bf16 (experts use raw x)
__global__ __launch_bounds__(256) void k_stats(const float* __restrict__ x, float2* __restrict__ stats,
                                               unsigned short* __restrict__ xb) {
  int tok = blockIdx.x, t = threadIdx.x;
  const float4 v = *reinterpret_cast<const float4*>(&x[(size_t)tok * H + (t << 2)]);
  float s = v.x + v.y + v.z + v.w;
  float ss = v.x * v.x + v.y * v.y + v.z * v.z + v.w * v.w;
#pragma unroll
  for (int off = 32; off; off >>= 1) { s += __shfl_down(s, off); ss += __shfl_down(ss, off); }
  __shared__ float red[4][2];
  int lane = t & 63, wv = t >> 6;
  if (lane == 0) { red[wv][0] = s; red[wv][1] = ss; }
  __syncthreads();
  float fs = red[0][0] + red[1][0] + red[2][0] + red[3][0];
  float fss = red[0][1] + red[1][1] + red[2][1] + red[3][1];
  float mean = fs * (1.0f / H);
  float var = fss * (1.0f / H) - mean * mean;
  float rstd = rsqrtf(var + 1e-5f);
  if (t == 0) stats[tok] = make_float2(mean, rstd);
  ushort4 ob;
  ob.x = f2bf(v.x); ob.y = f2bf(v.y); ob.z = f2bf(v.z); ob.w = f2bf(v.w);
  *reinterpret_cast<ushort4*>(&xb[(size_t)tok * H + (t << 2)]) = ob;
}

// Router GEMM on MFMA: hmid-tile = z @ (lsc*w1) via hi/lo bf16 split (3 passes), z=(x-m)*rstd.
// Epilogue: relu(tile + b1eff) @ w2 partials -> plog[nb*2+wavehalf][tok][E]. hmid never stored.
// 128x128 tile, BK=32, 4 waves 2x2, swizzled LDS, next-tile register prefetch.
__global__ __launch_bounds__(256) void k_router_mfma(
    const float* __restrict__ x, const float2* __restrict__ stats,
    const unsigned short* __restrict__ w1h, const unsigned short* __restrict__ w1l,
    const float* __restrict__ b1eff, const float* __restrict__ w2, float* __restrict__ plog) {
  __shared__ __align__(16) short Ah[4096], Al[4096], Bh[4096], Bl[4096];
  __shared__ float2 st[128];
  int t = threadIdx.x;
  int bm = blockIdx.x << 7, bn = blockIdx.y << 7;
  if (t < 128) st[t] = stats[bm + t];
  __syncthreads();
  int arow = t >> 1, ac0 = (t & 1) << 1;  // A: 16 k-floats per thread (chunks ac0, ac0+1)
  int brow = t >> 2, bc = t & 3;          // B: rows brow, brow+64, chunk bc
  float2 mr = st[arow];
  float rs = mr.y, mb = -mr.x * mr.y;
  const float* xsrc = &x[(size_t)(bm + arow) * H + (ac0 << 3)];
  const unsigned short* s1 = &w1h[(size_t)(bn + brow) * H + (bc << 3)];
  const unsigned short* s2 = &w1h[(size_t)(bn + brow + 64) * H + (bc << 3)];
  const unsigned short* s3 = &w1l[(size_t)(bn + brow) * H + (bc << 3)];
  const unsigned short* s4 = &w1l[(size_t)(bn + brow + 64) * H + (bc << 3)];
  float4 va0 = *(const float4*)(xsrc + 0), va1 = *(const float4*)(xsrc + 4);
  float4 va2 = *(const float4*)(xsrc + 8), va3 = *(const float4*)(xsrc + 12);
  int4 vb0 = *(const int4*)s1, vb1 = *(const int4*)s2, vb2 = *(const int4*)s3, vb3 = *(const int4*)s4;
  int lane = t & 63, wv = t >> 6;
  int wr = (wv >> 1) << 6, wc = (wv & 1) << 6;
  int l15 = lane & 15, lgp = lane >> 4;
  f32x4 acc[4][4];
#pragma unroll
  for (int i = 0; i < 4; ++i)
#pragma unroll
    for (int j = 0; j < 4; ++j) acc[i][j] = f32x4{0.f, 0.f, 0.f, 0.f};
  for (int kt = 0; kt < 32; ++kt) {
    // LN + truncation hi/lo split (in regs)
    float zz[16];
    zz[0] = fmaf(va0.x, rs, mb); zz[1] = fmaf(va0.y, rs, mb);
    zz[2] = fmaf(va0.z, rs, mb); zz[3] = fmaf(va0.w, rs, mb);
    zz[4] = fmaf(va1.x, rs, mb); zz[5] = fmaf(va1.y, rs, mb);
    zz[6] = fmaf(va1.z, rs, mb); zz[7] = fmaf(va1.w, rs, mb);
    zz[8] = fmaf(va2.x, rs, mb); zz[9] = fmaf(va2.y, rs, mb);
    zz[10] = fmaf(va2.z, rs, mb); zz[11] = fmaf(va2.w, rs, mb);
    zz[12] = fmaf(va3.x, rs, mb); zz[13] = fmaf(va3.y, rs, mb);
    zz[14] = fmaf(va3.z, rs, mb); zz[15] = fmaf(va3.w, rs, mb);
    unsigned hw[8], lw[8];
#pragma unroll
    for (int p = 0; p < 8; ++p) {
      unsigned ua = __float_as_uint(zz[2 * p]), ub = __float_as_uint(zz[2 * p + 1]);
      hw[p] = (ua >> 16) | (ub & 0xffff0000u);
      float la = zz[2 * p] - __uint_as_float(ua & 0xffff0000u);
      float lb = zz[2 * p + 1] - __uint_as_float(ub & 0xffff0000u);
      lw[p] = (__float_as_uint(la) >> 16) | (__float_as_uint(lb) & 0xffff0000u);
    }
    __syncthreads();  // previous iteration's fragment reads complete
    *(int4*)&Ah[swz(arow, ac0)] = make_int4(hw[0], hw[1], hw[2], hw[3]);
    *(int4*)&Ah[swz(arow, ac0 + 1)] = make_int4(hw[4], hw[5], hw[6], hw[7]);
    *(int4*)&Al[swz(arow, ac0)] = make_int4(lw[0], lw[1], lw[2], lw[3]);
    *(int4*)&Al[swz(arow, ac0 + 1)] = make_int4(lw[4], lw[5], lw[6], lw[7]);
    *(int4*)&Bh[swz(brow, bc)] = vb0;
    *(int4*)&Bh[swz(brow + 64, bc)] = vb1;
    *(int4*)&Bl[swz(brow, bc)] = vb2;
    *(int4*)&Bl[swz(brow + 64, bc)] = vb3;
    __syncthreads();
    if (kt + 1 < 32) {  // prefetch next k-tile into regs (hides under MFMA)
      xsrc += 32; s1 += 32; s2 += 32; s3 += 32; s4 += 32;
      va0 = *(const float4*)(xsrc + 0); va1 = *(const float4*)(xsrc + 4);
      va2 = *(const float4*)(xsrc + 8); va3 = *(const float4*)(xsrc + 12);
      vb0 = *(const int4*)s1; vb1 = *(const int4*)s2; vb2 = *(const int4*)s3; vb3 = *(const int4*)s4;
    }
    bf16x8 bh[4], bl[4];
#pragma unroll
    for (int j = 0; j < 4; ++j) {
      bh[j] = *(const bf16x8*)&Bh[swz(wc + (j << 4) + l15, lgp)];
      bl[j] = *(const bf16x8*)&Bl[swz(wc + (j << 4) + l15, lgp)];
    }
#pragma unroll
    for (int i = 0; i < 4; ++i) {
      bf16x8 ah = *(const bf16x8*)&Ah[swz(wr + (i << 4) + l15, lgp)];
      bf16x8 al = *(const bf16x8*)&Al[swz(wr + (i << 4) + l15, lgp)];
#pragma unroll
      for (int j = 0; j < 4; ++j) {
        acc[i][j] = __builtin_amdgcn_mfma_f32_16x16x32_bf16(ah, bh[j], acc[i][j], 0, 0, 0);
        acc[i][j] = __builtin_amdgcn_mfma_f32_16x16x32_bf16(ah, bl[j], acc[i][j], 0, 0, 0);
        acc[i][j] = __builtin_amdgcn_mfma_f32_16x16x32_bf16(al, bh[j], acc[i][j], 0, 0, 0);
      }
    }
  }
  // epilogue: bias + relu, then partial logits over this wave's 64 columns
  float w2r[4][8], b1r[4];
#pragma unroll
  for (int j = 0; j < 4; ++j) {
    int col = bn + wc + (j << 4) + l15;
    float4 p0 = *(const float4*)&w2[(size_t)col * E];
    float4 p1 = *(const float4*)&w2[(size_t)col * E + 4];
    w2r[j][0] = p0.x; w2r[j][1] = p0.y; w2r[j][2] = p0.z; w2r[j][3] = p0.w;
    w2r[j][4] = p1.x; w2r[j][5] = p1.y; w2r[j][6] = p1.z; w2r[j][7] = p1.w;
    b1r[j] = b1eff[col];
  }
#pragma unroll
  for (int i = 0; i < 4; ++i)
#pragma unroll
    for (int j = 0; j < 4; ++j)
#pragma unroll
      for (int r = 0; r < 4; ++r) acc[i][j][r] = fmaxf(acc[i][j][r] + b1r[j], 0.f);
  int wh = wc >> 6;
  size_t pbase = ((size_t)(blockIdx.y * 2 + wh) * TT + bm) * E;
#pragma unroll
  for (int e = 0; e < E; ++e) {
    float se[4][4];
#pragma unroll
    for (int i = 0; i < 4; ++i)
#pragma unroll
      for (int r = 0; r < 4; ++r)
        se[i][r] = acc[i][0][r] * w2r[0][e] + acc[i][1][r] * w2r[1][e] +
                   acc[i][2][r] * w2r[2][e] + acc[i][3][r] * w2r[3][e];
#pragma unroll
    for (int off = 1; off < 16; off <<= 1)
#pragma unroll
      for (int i = 0; i < 4; ++i)
#pragma unroll
        for (int r = 0; r < 4; ++r) se[i][r] += __shfl_xor(se[i][r], off);
    if (l15 == 0) {
#pragma unroll
      for (int i = 0; i < 4; ++i)
#pragma unroll
        for (int r = 0; r < 4; ++r) {
          int row = wr + (i << 4) + (lgp << 2) + r;
          plog[pbase + (size_t)row * E + e] = se[i][r];
        }
    }
  }
}

// thread-per-token: sum 16 logit partials + b2 -> softmax -> top2 -> renorm; wave-aggregated lists + psum
__global__ __launch_bounds__(256) void k_top(const float* __restrict__ plog, const float* __restrict__ b2,
                                             int* __restrict__ topE, float* __restrict__ topW,
                                             int* __restrict__ listIdx, float* __restrict__ listW,
                                             int* __restrict__ cnt, double* __restrict__ psum) {
  int t = threadIdx.x, lane = t & 63;
  int tok = (blockIdx.x << 8) + t;
  float lg[E], p[E];
  float4 ba = *reinterpret_cast<const float4*>(b2);
  float4 bb = *reinterpret_cast<const float4*>(b2 + 4);
  lg[0] = ba.x; lg[1] = ba.y; lg[2] = ba.z; lg[3] = ba.w;
  lg[4] = bb.x; lg[5] = bb.y; lg[6] = bb.z; lg[7] = bb.w;
#pragma unroll
  for (int nb = 0; nb < 16; ++nb) {
    const float* pp = &plog[((size_t)nb * TT + tok) * E];
    float4 q0 = *reinterpret_cast<const float4*>(pp);
    float4 q1 = *reinterpret_cast<const float4*>(pp + 4);
    lg[0] += q0.x; lg[1] += q0.y; lg[2] += q0.z; lg[3] += q0.w;
    lg[4] += q1.x; lg[5] += q1.y; lg[6] += q1.z; lg[7] += q1.w;
  }
  float m = lg[0];
#pragma unroll
  for (int e = 1; e < E; ++e) m = fmaxf(m, lg[e]);
  float s = 0.f;
#pragma unroll
  for (int e = 0; e < E; ++e) { p[e] = __expf(lg[e] - m); s += p[e]; }
  float inv = 1.f / s;
#pragma unroll
  for (int e = 0; e < E; ++e) p[e] *= inv;
  {
    float ps[E];
#pragma unroll
    for (int e = 0; e < E; ++e) ps[e] = p[e];
#pragma unroll
    for (int off = 1; off < 64; off <<= 1)
#pragma unroll
      for (int e = 0; e < E; ++e) ps[e] += __shfl_xor(ps[e], off);
    if (lane == 0)
#pragma unroll
      for (int e = 0; e < E; ++e) atomicAdd(&psum[e], (double)ps[e]);
  }
  int e0 = 0;
#pragma unroll
  for (int e = 1; e < E; ++e) if (p[e] > p[e0]) e0 = e;  // strict >: first max (jax tie order)
  int e1 = (e0 == 0) ? 1 : 0;
#pragma unroll
  for (int e = 0; e < E; ++e) if (e != e0 && p[e] > p[e1]) e1 = e;
  float rsw = 1.f / (p[e0] + p[e1]);
  float w0 = p[e0] * rsw, w1v = p[e1] * rsw;
  topE[tok << 1] = e0; topE[(tok << 1) + 1] = e1;
  topW[tok << 1] = w0; topW[(tok << 1) + 1] = w1v;
  unsigned long long lt = (1ull << lane) - 1ull;
#pragma unroll
  for (int e = 0; e < E; ++e) {
    unsigned long long m0 = __ballot(e0 == e);
    unsigned long long m1 = __ballot(e1 == e);
    int n0 = __popcll(m0), total = n0 + __popcll(m1);
    if (total == 0) continue;  // wave-uniform
    int leader = __ffsll(m0 | m1) - 1;
    int base = 0;
    if (lane == leader) base = atomicAdd(&cnt[e], total);
    base = __shfl(base, leader);
    if (e0 == e) {
      int pos = e * TT + base + __popcll(m0 & lt);
      listIdx[pos] = (tok << 1); listW[pos] = w0;
    }
    if (e1 == e) {
      int pos = e * TT + base + n0 + __popcll(m1 & lt);
      listIdx[pos] = (tok << 1) | 1; listW[pos] = w1v;
    }
  }
}

// grouped bf16 MFMA GEMM, swizzled LDS + register prefetch; weighted fp16 per-slot output
__global__ __launch_bounds__(256) void k_expert_gemm(const unsigned short* __restrict__ xb,
                                                     const unsigned short* __restrict__ wet,
                                                     const int* __restrict__ listIdx, const float* __restrict__ listW,
                                                     const int* __restrict__ cnt, unsigned short* __restrict__ ys) {
  int e = blockIdx.z;
  int c = cnt[e];
  int r0 = blockIdx.x << 7;
  if (r0 >= c) return;
  int n0 = blockIdx.y << 7;
  __shared__ __align__(16) short A[4096], B[4096];
  __shared__ int gi[128];
  __shared__ float gw[128];
  int t = threadIdx.x;
  if (t < 128) {
    int rr = r0 + t;
    gi[t] = (rr < c) ? listIdx[e * TT + rr] : -1;
    gw[t] = (rr < c) ? listW[e * TT + rr] : 0.f;
  }
  __syncthreads();
  int brow = t >> 2, bc = t & 3;
  int pk1 = gi[brow], pk2 = gi[brow + 64];
  int tokA1 = (pk1 < 0) ? 0 : (pk1 >> 1);
  int tokA2 = (pk2 < 0) ? 0 : (pk2 >> 1);
  const unsigned short* a1 = &xb[(size_t)tokA1 * H + (bc << 3)];
  const unsigned short* a2 = &xb[(size_t)tokA2 * H + (bc << 3)];
  size_t wbase = (size_t)e * H * H;
  const unsigned short* b1 = &wet[wbase + (size_t)(n0 + brow) * H + (bc << 3)];
  const unsigned short* b2 = &wet[wbase + (size_t)(n0 + brow + 64) * H + (bc << 3)];
  int4 va0 = *(const int4*)a1, va1 = *(const int4*)a2;
  int4 vb0 = *(const int4*)b1, vb1 = *(const int4*)b2;
  int lane = t & 63, wv = t >> 6;
  int wr = (wv >> 1) << 6, wc = (wv & 1) << 6;
  int l15 = lane & 15, lgp = lane >> 4;
  f32x4 acc[4][4];
#pragma unroll
  for (int i = 0; i < 4; ++i)
#pragma unroll
    for (int j = 0; j < 4; ++j) acc[i][j] = f32x4{0.f, 0.f, 0.f, 0.f};
  for (int kt = 0; kt < 32; ++kt) {
    __syncthreads();  // previous iteration's fragment reads complete
    *(int4*)&A[swz(brow, bc)] = va0;
    *(int4*)&A[swz(brow + 64, bc)] = va1;
    *(int4*)&B[swz(brow, bc)] = vb0;
    *(int4*)&B[swz(brow + 64, bc)] = vb1;
    __syncthreads();
    if (kt + 1 < 32) {
      a1 += 32; a2 += 32; b1 += 32; b2 += 32;
      va0 = *(const int4*)a1; va1 = *(const int4*)a2;
      vb0 = *(const int4*)b1; vb1 = *(const int4*)b2;
    }
    bf16x8 bq[4];
#pragma unroll
    for (int j = 0; j < 4; ++j) bq[j] = *(const bf16x8*)&B[swz(wc + (j << 4) + l15, lgp)];
#pragma unroll
    for (int i = 0; i < 4; ++i) {
      bf16x8 af = *(const bf16x8*)&A[swz(wr + (i << 4) + l15, lgp)];
#pragma unroll
      for (int j = 0; j < 4; ++j)
        acc[i][j] = __builtin_amdgcn_mfma_f32_16x16x32_bf16(af, bq[j], acc[i][j], 0, 0, 0);
    }
  }
#pragma unroll
  for (int i = 0; i < 4; ++i) {
#pragma unroll
    for (int r = 0; r < 4; ++r) {
      int row = wr + (i << 4) + (lgp << 2) + r;  // C/D: col=lane&15, row=(lane>>4)*4+reg
      int pk = gi[row];
      if (pk < 0) continue;
      int tok = pk >> 1, slot = pk & 1;
      float w = gw[row];
      size_t ob = ((size_t)slot * TT + tok) * H + n0 + wc + l15;
#pragma unroll
      for (int j = 0; j < 4; ++j) ys[ob + (j << 4)] = __half_as_ushort(__float2half(w * acc[i][j][r]));
    }
  }
}

// out = y_slot0 + y_slot1 + w0*be[e0] + w1*be[e1]
__global__ __launch_bounds__(256) void k_combine(const unsigned short* __restrict__ ys, const int* __restrict__ topE,
                                                 const float* __restrict__ topW, const float* __restrict__ be,
                                                 float* __restrict__ out) {
  int tok = blockIdx.x, t = threadIdx.x;
  int e0 = topE[tok << 1], e1 = topE[(tok << 1) + 1];
  float w0 = topW[tok << 1], w1v = topW[(tok << 1) + 1];
  int h = t << 2;
  size_t base = (size_t)tok * H + h;
  ushort4 a = *reinterpret_cast<const ushort4*>(&ys[base]);
  ushort4 b = *reinterpret_cast<const ushort4*>(&ys[(size_t)TT * H + base]);
  float4 b0 = *reinterpret_cast<const float4*>(&be[e0 * H + h]);
  float4 b1v = *reinterpret_cast<const float4*>(&be[e1 * H + h]);
  float4 o;
  o.x = __half2float(__ushort_as_half(a.x)) + __half2float(__ushort_as_half(b.x)) + w0 * b0.x + w1v * b1v.x;
  o.y = __half2float(__ushort_as_half(a.y)) + __half2float(__ushort_as_half(b.y)) + w0 * b0.y + w1v * b1v.y;
  o.z = __half2float(__ushort_as_half(a.z)) + __half2float(__ushort_as_half(b.z)) + w0 * b0.z + w1v * b1v.z;
  o.w = __half2float(__ushort_as_half(a.w)) + __half2float(__ushort_as_half(b.w)) + w0 * b0.w + w1v * b1v.w;
  *reinterpret_cast<float4*>(&out[base]) = o;
}

__global__ __launch_bounds__(64) void k_aux(const double* __restrict__ psum, float* __restrict__ outAux) {
  if (threadIdx.x == 0) {
    double a = 0.0;
    for (int e = 0; e < E; ++e) {
      double mp = psum[e] / (double)TT;
      a += mp * log(mp * (double)E + 1e-9);
    }
    outAux[0] = (float)a;
  }
}

extern "C" void kernel_launch(void* const* d_in, const int* in_sizes, int n_in, void* d_out, int out_size, void* d_ws,
                              size_t ws_size, hipStream_t stream) {
  const float* x = (const float*)d_in[0];
  const float* lsc = (const float*)d_in[1];
  const float* lbi = (const float*)d_in[2];
  const float* w1 = (const float*)d_in[3];
  const float* b1 = (const float*)d_in[4];
  const float* w2 = (const float*)d_in[5];
  const float* b2 = (const float*)d_in[6];
  const float* we = (const float*)d_in[7];
  const float* be = (const float*)d_in[8];
  float* out = (float*)d_out;
  char* ws = (char*)d_ws;

  // ws layout (peak 66 MB; 68.35 MB confirmed safe in R1/R2):
  // [0,2M): small; [2M,18M): xb bf16; [18M,34M): wet bf16; [34M,38M): w1h/w1l (dead after router);
  // [38M,42M): plog (dead after k_top); [34M,66M): ys fp16 [2][TT][H] (born at expert)
  char* p = ws;
  float2* stats = (float2*)p; p += TT * 8;
  int* topE = (int*)p; p += TT * 2 * 4;
  float* topW = (float*)p; p += TT * 2 * 4;
  int* listIdx = (int*)p; p += E * TT * 4;
  float* listW = (float*)p; p += E * TT * 4;
  int* cnt = (int*)p; p += 256;
  double* psum = (double*)p; p += 2048;
  float* b1eff = (float*)p; p += H * 4;
  float* part = (float*)p; p += 64 * H * 4;
  unsigned short* xb = (unsigned short*)(ws + (2u << 20));
  unsigned short* wet = (unsigned short*)(ws + (18u << 20));
  unsigned short* w1h = (unsigned short*)(ws + (34u << 20));
  unsigned short* w1l = (unsigned short*)(ws + (36u << 20));
  float* plog = (float*)(ws + (38u << 20));
  unsigned short* ys = (unsigned short*)(ws + (34u << 20));

  k_init<<<1, 64, 0, stream>>>(cnt, psum);
  k_cast_w1<<<dim3(32, 32), 256, 0, stream>>>(w1, lsc, w1h, w1l);
  k_b1a<<<64, 256, 0, stream>>>(w1, lbi, part);
  k_b1b<<<4, 256, 0, stream>>>(part, b1, b1eff);
  k_cast_we<<<dim3(32, 32, E), 256, 0, stream>>>(we, wet);
  k_stats<<<TT, 256, 0, stream>>>(x, stats, xb);
  k_router_mfma<<<dim3(TT / 128, H / 128), 256, 0, stream>>>(x, stats, w1h, w1l, b1eff, w2, plog);
  k_top<<<TT / 256, 256, 0, stream>>>(plog, b2, topE, topW, listIdx, listW, cnt, psum);
  k_expert_gemm<<<dim3(TT / 128, H / 128, E), 256, 0, stream>>>(xb, wet, listIdx, listW, cnt, ys);
  k_combine<<<TT, 256, 0, stream>>>(ys, topE, topW, be, out);
  k_aux<<<1, 64, 0, stream>>>(psum, out + (size_t)TT * H);
}